// Round 2
// baseline (363.071 us; speedup 1.0000x reference)
//
#include <hip/hip_runtime.h>
#include <hip/hip_bf16.h>

typedef float v4f __attribute__((ext_vector_type(4)));

#define B_ 4
#define M_ 1024
#define ND_ 64
#define ED_ 8
#define D_ 64
#define H_ 4
#define KT 8           // k-rows per block
#define QC 64          // q-chunk
#define NCH (M_ / QC)  // 16 chunks
#define ALPHA 0.2f

// ws layout (floats): Wh [B][H][M][D], Wh1 [B][H][M], Wh2 [B][H][M], w_e [H][ED]
#define WS_WH1 1048576
#define WS_WH2 1064960
#define WS_WE  1081344

// k_main LDS layout (floats)
#define WHL_STRIDE 260            // 256 + 4 pad -> bank-optimal rows
#define WHL_F (QC * WHL_STRIDE)   // 16640
#define PB_H 520                  // KT*QC + 8 pad
#define PB_F (H_ * PB_H)          // 2080
#define LDS_BYTES ((WHL_F + PB_F + 32 + 32) * 4)  // 75136

__device__ __forceinline__ v4f splat(float s) { return (v4f){s, s, s, s}; }

__device__ __forceinline__ v4f f4fma(v4f a, v4f b, v4f c) {
#if __has_builtin(__builtin_elementwise_fma)
    return __builtin_elementwise_fma(a, b, c);
#else
    v4f r;
    r.x = fmaf(a.x, b.x, c.x);
    r.y = fmaf(a.y, b.y, c.y);
    r.z = fmaf(a.z, b.z, c.z);
    r.w = fmaf(a.w, b.w, c.w);
    return r;
#endif
}

// ---------------- kernel 1: Wh, Wh1, Wh2 ----------------
// grid B*H*(M/16) = 1024 blocks x 256. thread = (m:16, d4:16) for one (b,h).
__global__ __launch_bounds__(256) void k_pre(const float* __restrict__ hg,
                                             const float* __restrict__ Wg,
                                             const float* __restrict__ ag,
                                             float* __restrict__ Whg,
                                             float* __restrict__ Wh1g,
                                             float* __restrict__ Wh2g) {
    __shared__ float wl[ND_ * D_];  // 16 KB, linear [i][d]
    __shared__ float hl[16 * 68];   // padded rows (stride 68)
    const int t = threadIdx.x, lane = t & 63, wv = t >> 6;
    const int bid = blockIdx.x;
    const int b = bid >> 8, h = (bid >> 6) & (H_ - 1), mb = bid & 63;
    const int m0 = mb * 16;

    // stage W[h] (16 KB) via async global->LDS, 4 KB per wave
    {
        const float* wsrc = Wg + h * ND_ * D_;
#pragma unroll
        for (int i = 0; i < 4; ++i) {
            const float* s = wsrc + (wv * 4 + i) * 256 + lane * 4;
            __builtin_amdgcn_global_load_lds(
                (const __attribute__((address_space(1))) void*)s,
                (__attribute__((address_space(3))) void*)(wl + (wv * 4 + i) * 256), 16, 0, 0);
        }
    }
    // stage h tile (reg -> padded LDS)
    {
        const int mh = t >> 4, u = t & 15;
        v4f hv = *(const v4f*)(hg + ((size_t)(b * M_) + m0 + mh) * ND_ + u * 4);
        *(v4f*)(hl + mh * 68 + u * 4) = hv;
    }
    __syncthreads();

    const int m = t >> 4, d4 = t & 15;
    v4f acc = {0.f, 0.f, 0.f, 0.f};
#pragma unroll
    for (int i = 0; i < ND_; ++i) {
        v4f w4 = *(const v4f*)(wl + i * 64 + d4 * 4);
        float hs = hl[m * 68 + i];
        acc = f4fma(splat(hs), w4, acc);
    }
    *(v4f*)(Whg + (((size_t)(b * H_ + h)) * M_ + m0 + m) * D_ + d4 * 4) = acc;

    // fused a1/a2 projections (reduce across the 16 d4 lanes of each m)
    v4f a1 = *(const v4f*)(ag + h * 192 + d4 * 4);
    v4f a2 = *(const v4f*)(ag + h * 192 + 64 + d4 * 4);
    v4f p1 = acc * a1, p2 = acc * a2;
    float r1 = (p1.x + p1.y) + (p1.z + p1.w);
    float r2 = (p2.x + p2.y) + (p2.z + p2.w);
#pragma unroll
    for (int off = 8; off >= 1; off >>= 1) {
        r1 += __shfl_xor(r1, off);
        r2 += __shfl_xor(r2, off);
    }
    if (d4 == 0) {
        Wh1g[((size_t)(b * H_ + h)) * M_ + m0 + m] = r1;
        Wh2g[((size_t)(b * H_ + h)) * M_ + m0 + m] = r2;
    }
}

// ---------------- kernel 2: w_e ----------------
__global__ void k_we(const float* __restrict__ Weg, const float* __restrict__ ag,
                     float* __restrict__ weg) {
    const int t = threadIdx.x;
    if (t < H_ * ED_) {
        const int h = t >> 3, e = t & 7;
        const float* wrow = Weg + (h * ED_ + e) * D_;
        const float* a3 = ag + h * 192 + 128;
        float acc = 0.f;
#pragma unroll
        for (int i = 0; i < D_; ++i) acc = fmaf(wrow[i], a3[i], acc);
        weg[t] = acc;
    }
}

// ---------------- kernel 3: fused e -> softmax -> PV ----------------
// grid 512 x 512 (2 blocks/CU). block = (b, 8 k-rows), 8 waves.
// e-phase : wave wv owns k-row k0+wv, lane = q within chunk.
// PV      : wave wv owns q in [wv*8, wv*8+8); acc[8] covers k x (hh,d4).
// Schedule per chunk: e | barrierA | prefetch(c+1) | PV | barrierB | ds_write whl.
// All loads are issued ~a full PV phase before any barrier's vmcnt(0) drain.
__global__ __launch_bounds__(512, 4) void k_main(const float* __restrict__ cvg,
                                                 const int* __restrict__ mg,
                                                 const float* __restrict__ Whg,
                                                 const float* __restrict__ Wh1g,
                                                 const float* __restrict__ Wh2g,
                                                 const float* __restrict__ weg,
                                                 float* __restrict__ outg) {
    extern __shared__ float smem[];
    float* whl = smem;             // [64][260]
    float* pb = smem + WHL_F;      // [H][520]  ([h][k*64+q])
    float* wel = pb + PB_F;        // 32
    float* sl = wel + 32;          // 32  ([k][h])

    const int t = threadIdx.x, lane = t & 63, wv = t >> 6;
    const int b = blockIdx.x >> 7;
    const int k0 = (blockIdx.x & 127) * KT;
    const int hh = lane >> 4, d4 = lane & 15;

    if (t < 32) wel[t] = weg[t];

    const int ek = k0 + wv;
    float wh1r[H_];
#pragma unroll
    for (int h = 0; h < H_; ++h) wh1r[h] = Wh1g[(b * H_ + h) * M_ + ek];

    const v4f* cvrow = (const v4f*)(cvg + (size_t)(b * M_ + ek) * M_ * ED_);
    const int* mrow = mg + (size_t)(b * M_ + ek) * M_;

    // Wh staging mapping: thread -> (row sq, piece sp); piece = (h, d-half)
    const int sq = t >> 3, sp = t & 7;
    const float* wh_src = Whg + ((size_t)(b * H_ + (sp >> 1)) * M_) * D_ + (sp & 1) * 32;
    float* wh_dst = whl + sq * WHL_STRIDE + sp * 32;  // 8 consecutive float4

    v4f acc[KT];
#pragma unroll
    for (int k = 0; k < KT; ++k) acc[k] = (v4f){0.f, 0.f, 0.f, 0.f};
    float sreg[H_] = {0.f, 0.f, 0.f, 0.f};

    // ---- prologue: chunk-0 regs + whl(0) staged ----
    v4f cv0 = cvrow[lane * 2], cv1 = cvrow[lane * 2 + 1];
    int mk = mrow[lane];
    float wh2r[H_];
#pragma unroll
    for (int h = 0; h < H_; ++h) wh2r[h] = Wh2g[(b * H_ + h) * M_ + lane];
    v4f wreg[8];
    {
        const v4f* s = (const v4f*)(wh_src + (size_t)sq * D_);
#pragma unroll
        for (int i = 0; i < 8; ++i) wreg[i] = s[i];
#pragma unroll
        for (int i = 0; i < 8; ++i) ((v4f*)wh_dst)[i] = wreg[i];
    }
    __syncthreads();

    for (int c = 0; c < NCH; ++c) {
        // ---- e-phase: p = exp(leaky(Wh1 + Wh2 + cv.w_e)) masked ----
#pragma unroll
        for (int h = 0; h < H_; ++h) {
            v4f wa = *(const v4f*)(wel + h * 8);
            v4f wb = *(const v4f*)(wel + h * 8 + 4);
            v4f tt = cv0 * wa + cv1 * wb;
            float ef = (tt.x + tt.y) + (tt.z + tt.w);
            float e = wh1r[h] + wh2r[h] + ef;
            e = fmaxf(e, ALPHA * e);
            float p = (mk > 0) ? __expf(e) : 0.0f;
            pb[h * PB_H + wv * QC + lane] = p;
            sreg[h] += p;
        }
        __syncthreads();  // A: pb + whl(c) visible; nothing in flight -> free drain

        // ---- prefetch chunk c+1 (lands during PV) ----
        if (c + 1 < NCH) {
            const int qn = (c + 1) * QC + lane;
            cv0 = cvrow[qn * 2];
            cv1 = cvrow[qn * 2 + 1];
            mk = mrow[qn];
#pragma unroll
            for (int h = 0; h < H_; ++h) wh2r[h] = Wh2g[(b * H_ + h) * M_ + qn];
            const v4f* s = (const v4f*)(wh_src + (size_t)((c + 1) * QC + sq) * D_);
#pragma unroll
            for (int i = 0; i < 8; ++i) wreg[i] = s[i];
        }

        // ---- PV: acc[k] += p[hh][k][q] * Wh[q][hh][d] ----
        {
            const int q0 = wv * 8;
#pragma unroll
            for (int qq = 0; qq < 2; ++qq) {
                const int q = q0 + qq * 4;
                const v4f w0 = *(const v4f*)(whl + (q + 0) * WHL_STRIDE + lane * 4);
                const v4f w1 = *(const v4f*)(whl + (q + 1) * WHL_STRIDE + lane * 4);
                const v4f w2 = *(const v4f*)(whl + (q + 2) * WHL_STRIDE + lane * 4);
                const v4f w3 = *(const v4f*)(whl + (q + 3) * WHL_STRIDE + lane * 4);
                const float* pbase = pb + hh * PB_H + q;
#pragma unroll
                for (int k = 0; k < KT; ++k) {
                    v4f pq = *(const v4f*)(pbase + k * 64);
                    v4f a = acc[k];
                    a = f4fma(splat(pq.x), w0, a);
                    a = f4fma(splat(pq.y), w1, a);
                    a = f4fma(splat(pq.z), w2, a);
                    a = f4fma(splat(pq.w), w3, a);
                    acc[k] = a;
                }
            }
        }
        __syncthreads();  // B: whl reads done; prefetch already landed -> free drain

        // ---- write staged whl(c+1) ----
        if (c + 1 < NCH) {
#pragma unroll
            for (int i = 0; i < 8; ++i) ((v4f*)wh_dst)[i] = wreg[i];
        }
    }

    // ---- epilogue ----
    // softmax denominators (once): butterfly over all 64 q-lanes
#pragma unroll
    for (int h = 0; h < H_; ++h) {
        float r = sreg[h];
#pragma unroll
        for (int off = 32; off >= 1; off >>= 1) r += __shfl_xor(r, off);
        if (lane == 0) sl[wv * H_ + h] = r;
    }
    // partial accs -> whl rows [wv*8 + k]
#pragma unroll
    for (int k = 0; k < KT; ++k)
        *(v4f*)(whl + (wv * KT + k) * WHL_STRIDE + lane * 4) = acc[k];
    __syncthreads();
    // combine 8 q-partials for k = wv, scale, write
    {
        v4f r = (v4f){0.f, 0.f, 0.f, 0.f};
#pragma unroll
        for (int p = 0; p < 8; ++p)
            r += *(const v4f*)(whl + (p * KT + wv) * WHL_STRIDE + lane * 4);
        const float inv = 1.0f / sl[wv * H_ + hh];
        r *= splat(inv);
        *(v4f*)(outg + (size_t)(b * M_ + k0 + wv) * (H_ * D_) + lane * 4) = r;
    }
}

extern "C" void kernel_launch(void* const* d_in, const int* in_sizes, int n_in,
                              void* d_out, int out_size, void* d_ws, size_t ws_size,
                              hipStream_t stream) {
    const float* hg = (const float*)d_in[0];
    const int* mg = (const int*)d_in[1];
    const float* cvg = (const float*)d_in[2];
    const float* Wg = (const float*)d_in[3];
    const float* Weg = (const float*)d_in[4];
    const float* ag = (const float*)d_in[5];
    float* outg = (float*)d_out;
    float* ws = (float*)d_ws;
    float* Whg = ws;
    float* Wh1g = ws + WS_WH1;
    float* Wh2g = ws + WS_WH2;
    float* weg = ws + WS_WE;

    (void)hipFuncSetAttribute((const void*)k_main,
                              hipFuncAttributeMaxDynamicSharedMemorySize, LDS_BYTES);

    k_pre<<<1024, 256, 0, stream>>>(hg, Wg, ag, Whg, Wh1g, Wh2g);
    k_we<<<1, 64, 0, stream>>>(Weg, ag, weg);
    k_main<<<512, 512, LDS_BYTES, stream>>>(cvg, mg, Whg, Wh1g, Wh2g, weg, outg);
}

// Round 6
// 252.578 us; speedup vs baseline: 1.4375x; 1.4375x over previous
//
#include <hip/hip_runtime.h>
#include <hip/hip_bf16.h>

typedef float v4f __attribute__((ext_vector_type(4)));

#define B_ 4
#define M_ 1024
#define ND_ 64
#define ED_ 8
#define D_ 64
#define H_ 4
#define KT 8           // k-rows per block
#define QC 64          // q-chunk
#define NCH (M_ / QC)  // 16 chunks
#define ALPHA 0.2f

// ws layout (floats): Wh [B][H][M][D], Wh1 [B][H][M], Wh2 [B][H][M]
#define WS_WH1 1048576
#define WS_WH2 1064960

// k_main LDS layout (floats). whl rows are 256f (1024B) -> linear lane x 16B
// (global_load_lds requirement) and conflict-free ds_read_b128 (round-1: 0 conflicts).
#define WHL_F (QC * 256)  // 16384
#define PB_H 520          // KT*QC + 8
#define PB_F (H_ * PB_H)  // 2080
#define LDS_BYTES ((WHL_F + PB_F + 32 + 32) * 4)  // 74112 -> 2 blocks/CU

__device__ __forceinline__ v4f splat(float s) { return (v4f){s, s, s, s}; }

__device__ __forceinline__ v4f f4fma(v4f a, v4f b, v4f c) {
#if __has_builtin(__builtin_elementwise_fma)
    return __builtin_elementwise_fma(a, b, c);
#else
    v4f r;
    r.x = fmaf(a.x, b.x, c.x);
    r.y = fmaf(a.y, b.y, c.y);
    r.z = fmaf(a.z, b.z, c.z);
    r.w = fmaf(a.w, b.w, c.w);
    return r;
#endif
}

// ---------------- kernel 1: Wh, Wh1, Wh2 ----------------
// grid B*H*(M/16) = 1024 blocks x 256. thread = (m:16, d4:16) for one (b,h).
__global__ __launch_bounds__(256) void k_pre(const float* __restrict__ hg,
                                             const float* __restrict__ Wg,
                                             const float* __restrict__ ag,
                                             float* __restrict__ Whg,
                                             float* __restrict__ Wh1g,
                                             float* __restrict__ Wh2g) {
    __shared__ float wl[ND_ * D_];  // 16 KB, linear [i][d]
    __shared__ float hl[16 * 68];   // padded rows (stride 68)
    const int t = threadIdx.x, lane = t & 63, wv = t >> 6;
    const int bid = blockIdx.x;
    const int b = bid >> 8, h = (bid >> 6) & (H_ - 1), mb = bid & 63;
    const int m0 = mb * 16;

    // stage W[h] (16 KB) via async global->LDS, 4 KB per wave
    {
        const float* wsrc = Wg + h * ND_ * D_;
#pragma unroll
        for (int i = 0; i < 4; ++i) {
            const float* s = wsrc + (wv * 4 + i) * 256 + lane * 4;
            __builtin_amdgcn_global_load_lds(
                (const __attribute__((address_space(1))) void*)s,
                (__attribute__((address_space(3))) void*)(wl + (wv * 4 + i) * 256), 16, 0, 0);
        }
    }
    // stage h tile (reg -> padded LDS)
    {
        const int mh = t >> 4, u = t & 15;
        v4f hv = *(const v4f*)(hg + ((size_t)(b * M_) + m0 + mh) * ND_ + u * 4);
        *(v4f*)(hl + mh * 68 + u * 4) = hv;
    }
    __syncthreads();

    const int m = t >> 4, d4 = t & 15;
    v4f acc = {0.f, 0.f, 0.f, 0.f};
#pragma unroll
    for (int i = 0; i < ND_; ++i) {
        v4f w4 = *(const v4f*)(wl + i * 64 + d4 * 4);
        float hs = hl[m * 68 + i];
        acc = f4fma(splat(hs), w4, acc);
    }
    *(v4f*)(Whg + (((size_t)(b * H_ + h)) * M_ + m0 + m) * D_ + d4 * 4) = acc;

    // fused a1/a2 projections (reduce across the 16 d4 lanes of each m)
    v4f a1 = *(const v4f*)(ag + h * 192 + d4 * 4);
    v4f a2 = *(const v4f*)(ag + h * 192 + 64 + d4 * 4);
    v4f p1 = acc * a1, p2 = acc * a2;
    float r1 = (p1.x + p1.y) + (p1.z + p1.w);
    float r2 = (p2.x + p2.y) + (p2.z + p2.w);
#pragma unroll
    for (int off = 8; off >= 1; off >>= 1) {
        r1 += __shfl_xor(r1, off);
        r2 += __shfl_xor(r2, off);
    }
    if (d4 == 0) {
        Wh1g[((size_t)(b * H_ + h)) * M_ + m0 + m] = r1;
        Wh2g[((size_t)(b * H_ + h)) * M_ + m0 + m] = r2;
    }
}

// ---------------- kernel 2: fused e -> softmax -> PV ----------------
// grid 512 x 512, 2 blocks/CU. Bijective chunked XCD swizzle -> each XCD's
// blocks share one b (Wh[b] = 1 MB resident in that XCD's 4 MB L2).
// block = (b, 8 k-rows), 8 waves.
// e-phase : wave wv owns k-row k0+wv, lane = q within chunk.
// PV      : wave wv owns q in [wv*8, wv*8+8) for ALL 8 k (each whl row read
//           by exactly one wave -> 64 KB LDS/chunk, vs 512 KB in round 1).
// Barrier discipline (every vmcnt(0) drain covers loads issued a phase ago):
//   e(c) | A | cv-prefetch(c+1) | PV(c) | B | global_load_lds whl(c+1) | ...
__global__ __launch_bounds__(512, 4) void k_main(const float* __restrict__ cvg,
                                                 const int* __restrict__ mg,
                                                 const float* __restrict__ Whg,
                                                 const float* __restrict__ Wh1g,
                                                 const float* __restrict__ Wh2g,
                                                 const float* __restrict__ Weg,
                                                 const float* __restrict__ ag,
                                                 float* __restrict__ outg) {
    extern __shared__ float smem[];
    float* whl = smem;            // [64][256]
    float* pb = smem + WHL_F;     // [H][520]  ([h][k*64+q])
    float* wel = pb + PB_F;       // 32
    float* sl = wel + 32;         // 32  ([k][h])

    const int t = threadIdx.x, lane = t & 63, wv = t >> 6;
    const int nid = (blockIdx.x & 7) * 64 + (blockIdx.x >> 3);  // chunked XCD swizzle
    const int b = nid >> 7;
    const int k0 = (nid & 127) * KT;
    const int hh = lane >> 4, d4 = lane & 15;

    // fused w_e (was kernel k_we): 32 threads, 64-step dot each
    if (t < 32) {
        const int h = t >> 3, e = t & 7;
        const float* wrow = Weg + (h * ED_ + e) * D_;
        const float* a3 = ag + h * 192 + 128;
        float a = 0.f;
#pragma unroll
        for (int i = 0; i < D_; ++i) a = fmaf(wrow[i], a3[i], a);
        wel[t] = a;
    }

    const int ek = k0 + wv;
    float wh1r[H_];
#pragma unroll
    for (int h = 0; h < H_; ++h) wh1r[h] = Wh1g[(b * H_ + h) * M_ + ek];

    const v4f* cvrow = (const v4f*)(cvg + (size_t)(b * M_ + ek) * M_ * ED_);
    const int* mrow = mg + (size_t)(b * M_ + ek) * M_;

    v4f acc[KT];
#pragma unroll
    for (int k = 0; k < KT; ++k) acc[k] = (v4f){0.f, 0.f, 0.f, 0.f};
    float sreg[H_] = {0.f, 0.f, 0.f, 0.f};

    // ---- prologue: stage whl(0) (DMA) + cv(0) regs ----
#pragma unroll
    for (int i = 0; i < KT; ++i) {
        const int q = wv * KT + i;
        const float* src = Whg + ((size_t)(b * H_ + hh) * M_ + q) * D_ + d4 * 4;
        __builtin_amdgcn_global_load_lds((const __attribute__((address_space(1))) void*)src,
                                         (__attribute__((address_space(3))) void*)(whl + q * 256),
                                         16, 0, 0);
    }
    v4f cv0 = cvrow[lane * 2], cv1 = cvrow[lane * 2 + 1];
    int mk = mrow[lane];
    float wh2r[H_];
#pragma unroll
    for (int h = 0; h < H_; ++h) wh2r[h] = Wh2g[(b * H_ + h) * M_ + lane];
    __syncthreads();

    for (int c = 0; c < NCH; ++c) {
        // ---- e-phase: p = exp(leaky(Wh1 + Wh2 + cv.w_e)) masked ----
#pragma unroll
        for (int h = 0; h < H_; ++h) {
            v4f wa = *(const v4f*)(wel + h * 8);
            v4f wb = *(const v4f*)(wel + h * 8 + 4);
            v4f tt = cv0 * wa + cv1 * wb;
            float ef = (tt.x + tt.y) + (tt.z + tt.w);
            float e = wh1r[h] + wh2r[h] + ef;
            e = fmaxf(e, ALPHA * e);
            float p = (mk > 0) ? __expf(e) : 0.0f;
            pb[h * PB_H + wv * QC + lane] = p;
            sreg[h] += p;
        }
        __syncthreads();  // A: pb visible; whl(c) staging (issued a phase ago) drained

        // ---- cv prefetch(c+1): in flight across PV, drained at B ----
        if (c + 1 < NCH) {
            const int qn = (c + 1) * QC + lane;
            cv0 = cvrow[qn * 2];
            cv1 = cvrow[qn * 2 + 1];
            mk = mrow[qn];
#pragma unroll
            for (int h = 0; h < H_; ++h) wh2r[h] = Wh2g[(b * H_ + h) * M_ + qn];
        }

        // ---- PV: acc[k] += p[hh][k][q] * Wh[q][hh][d], q in wave's slice ----
        {
            const int q0 = wv * 8;
#pragma unroll
            for (int qq = 0; qq < 2; ++qq) {
                const int q = q0 + qq * 4;
                const v4f w0 = *(const v4f*)(whl + (q + 0) * 256 + lane * 4);
                const v4f w1 = *(const v4f*)(whl + (q + 1) * 256 + lane * 4);
                const v4f w2 = *(const v4f*)(whl + (q + 2) * 256 + lane * 4);
                const v4f w3 = *(const v4f*)(whl + (q + 3) * 256 + lane * 4);
                const float* pbase = pb + hh * PB_H + q;
#pragma unroll
                for (int k = 0; k < KT; ++k) {
                    const v4f pq = *(const v4f*)(pbase + k * 64);  // broadcast
                    v4f a = acc[k];
                    a = f4fma(splat(pq.x), w0, a);
                    a = f4fma(splat(pq.y), w1, a);
                    a = f4fma(splat(pq.z), w2, a);
                    a = f4fma(splat(pq.w), w3, a);
                    acc[k] = a;
                }
            }
        }
        __syncthreads();  // B: whl reads done; cv(c+1) drained (in flight across PV)

        // ---- stage whl(c+1) (DMA): in flight across next e-phase ----
        if (c + 1 < NCH) {
#pragma unroll
            for (int i = 0; i < KT; ++i) {
                const int q = wv * KT + i;
                const float* src =
                    Whg + ((size_t)(b * H_ + hh) * M_ + (c + 1) * QC + q) * D_ + d4 * 4;
                __builtin_amdgcn_global_load_lds(
                    (const __attribute__((address_space(1))) void*)src,
                    (__attribute__((address_space(3))) void*)(whl + q * 256), 16, 0, 0);
            }
        }
    }

    // ---- epilogue ----
    // softmax denominators (once per kernel, not per chunk)
#pragma unroll
    for (int h = 0; h < H_; ++h) {
        float r = sreg[h];
#pragma unroll
        for (int off = 32; off >= 1; off >>= 1) r += __shfl_xor(r, off);
        if (lane == 0) sl[wv * H_ + h] = r;
    }
    // q-slice partials -> whl rows [wv*8 + k]
#pragma unroll
    for (int k = 0; k < KT; ++k)
        *(v4f*)(whl + (wv * KT + k) * 256 + lane * 4) = acc[k];
    __syncthreads();
    // combine the 8 q-partials for k-row wv, scale, write
    {
        v4f r = (v4f){0.f, 0.f, 0.f, 0.f};
#pragma unroll
        for (int p = 0; p < 8; ++p)
            r += *(const v4f*)(whl + (p * KT + wv) * 256 + lane * 4);
        const float inv = 1.0f / sl[wv * H_ + hh];
        r *= splat(inv);
        *(v4f*)(outg + (size_t)(b * M_ + k0 + wv) * (H_ * D_) + lane * 4) = r;
    }
}

extern "C" void kernel_launch(void* const* d_in, const int* in_sizes, int n_in,
                              void* d_out, int out_size, void* d_ws, size_t ws_size,
                              hipStream_t stream) {
    const float* hg = (const float*)d_in[0];
    const int* mg = (const int*)d_in[1];
    const float* cvg = (const float*)d_in[2];
    const float* Wg = (const float*)d_in[3];
    const float* Weg = (const float*)d_in[4];
    const float* ag = (const float*)d_in[5];
    float* outg = (float*)d_out;
    float* ws = (float*)d_ws;
    float* Whg = ws;
    float* Wh1g = ws + WS_WH1;
    float* Wh2g = ws + WS_WH2;

    (void)hipFuncSetAttribute((const void*)k_main,
                              hipFuncAttributeMaxDynamicSharedMemorySize, LDS_BYTES);

    k_pre<<<1024, 256, 0, stream>>>(hg, Wg, ag, Whg, Wh1g, Wh2g);
    k_main<<<512, 512, LDS_BYTES, stream>>>(cvg, mg, Whg, Wh1g, Wh2g, Weg, ag, outg);
}

// Round 8
// 247.492 us; speedup vs baseline: 1.4670x; 1.0206x over previous
//
#include <hip/hip_runtime.h>
#include <hip/hip_bf16.h>

typedef float v4f __attribute__((ext_vector_type(4)));

#define B_ 4
#define M_ 1024
#define ND_ 64
#define ED_ 8
#define D_ 64
#define H_ 4
#define KT 8           // k-rows per block
#define QC 64          // q-chunk
#define NCH (M_ / QC)  // 16 chunks
#define ALPHA 0.2f

// ws layout (floats): Wh [B][H][M][D], Wh1p [B][M][H], Wh2p [B][M][H]
#define WS_WH1 1048576
#define WS_WH2 1064960

#define PB_H 520          // KT*QC + 8 pad (8-bank shift between h-planes)
#define PB_F (H_ * PB_H)  // 2080

__device__ __forceinline__ v4f splat(float s) { return (v4f){s, s, s, s}; }

__device__ __forceinline__ v4f f4fma(v4f a, v4f b, v4f c) {
#if __has_builtin(__builtin_elementwise_fma)
    return __builtin_elementwise_fma(a, b, c);
#else
    v4f r;
    r.x = fmaf(a.x, b.x, c.x);
    r.y = fmaf(a.y, b.y, c.y);
    r.z = fmaf(a.z, b.z, c.z);
    r.w = fmaf(a.w, b.w, c.w);
    return r;
#endif
}

// ---------------- kernel 1: Wh, Wh1p, Wh2p ----------------
// grid B*H*(M/16) = 1024 blocks x 256. thread = (m:16, d4:16) for one (b,h).
__global__ __launch_bounds__(256) void k_pre(const float* __restrict__ hg,
                                             const float* __restrict__ Wg,
                                             const float* __restrict__ ag,
                                             float* __restrict__ Whg,
                                             float* __restrict__ Wh1g,
                                             float* __restrict__ Wh2g) {
    __shared__ float wl[ND_ * D_];  // 16 KB, linear [i][d]
    __shared__ float hl[16 * 68];   // padded rows (stride 68)
    const int t = threadIdx.x, lane = t & 63, wv = t >> 6;
    const int bid = blockIdx.x;
    const int b = bid >> 8, h = (bid >> 6) & (H_ - 1), mb = bid & 63;
    const int m0 = mb * 16;

    // stage W[h] (16 KB) via async global->LDS, 4 KB per wave
    {
        const float* wsrc = Wg + h * ND_ * D_;
#pragma unroll
        for (int i = 0; i < 4; ++i) {
            const float* s = wsrc + (wv * 4 + i) * 256 + lane * 4;
            __builtin_amdgcn_global_load_lds(
                (const __attribute__((address_space(1))) void*)s,
                (__attribute__((address_space(3))) void*)(wl + (wv * 4 + i) * 256), 16, 0, 0);
        }
    }
    // stage h tile (reg -> padded LDS)
    {
        const int mh = t >> 4, u = t & 15;
        v4f hv = *(const v4f*)(hg + ((size_t)(b * M_) + m0 + mh) * ND_ + u * 4);
        *(v4f*)(hl + mh * 68 + u * 4) = hv;
    }
    __syncthreads();

    const int m = t >> 4, d4 = t & 15;
    v4f acc = {0.f, 0.f, 0.f, 0.f};
#pragma unroll
    for (int i = 0; i < ND_; ++i) {
        v4f w4 = *(const v4f*)(wl + i * 64 + d4 * 4);
        float hs = hl[m * 68 + i];
        acc = f4fma(splat(hs), w4, acc);
    }
    *(v4f*)(Whg + (((size_t)(b * H_ + h)) * M_ + m0 + m) * D_ + d4 * 4) = acc;

    // fused a1/a2 projections (reduce across the 16 d4 lanes of each m)
    v4f a1 = *(const v4f*)(ag + h * 192 + d4 * 4);
    v4f a2 = *(const v4f*)(ag + h * 192 + 64 + d4 * 4);
    v4f p1 = acc * a1, p2 = acc * a2;
    float r1 = (p1.x + p1.y) + (p1.z + p1.w);
    float r2 = (p2.x + p2.y) + (p2.z + p2.w);
#pragma unroll
    for (int off = 8; off >= 1; off >>= 1) {
        r1 += __shfl_xor(r1, off);
        r2 += __shfl_xor(r2, off);
    }
    // packed layout [b][m][h] -> k_main prefetches one coalesced v4f per lane
    if (d4 == 0) {
        Wh1g[((size_t)(b * M_) + m0 + m) * H_ + h] = r1;
        Wh2g[((size_t)(b * M_) + m0 + m) * H_ + h] = r2;
    }
}

// ---------------- kernel 2: fused e -> softmax -> PV ----------------
// grid 512 x 512, 2 blocks/CU. Bijective chunked XCD swizzle (512 = 8*64) ->
// each XCD's blocks share one b (Wh[b] = 1 MB resident in its 4 MB L2).
// block = (b, 8 k-rows), 8 waves. NO Wh LDS staging: each whl row was read by
// exactly one wave, so PV reads Wh straight from L2 into v4f regs (same global
// traffic, no DMA, no second barrier, LDS 74->49.7 KB).
// pb is double-buffered -> ONE barrier per chunk:
//   e(c)->pb[c&1] | barrier | prefetch(c+1) | PV(c) reads pb[c&1] + Wh(L2) | ...
// Safety: e(c+1) writes pb[(c+1)&1]; any wave reaching e(c+2) (writing pb[c&1]
// again) must have passed barrier(c+1), which no wave passes until every wave
// finished PV(c) -> no overlap. Epilogue combines via 32 KB scr in two
// half-passes.
__global__ __launch_bounds__(512, 4) void k_main(const float* __restrict__ cvg,
                                                 const int* __restrict__ mg,
                                                 const float* __restrict__ Whg,
                                                 const float* __restrict__ Wh1g,
                                                 const float* __restrict__ Wh2g,
                                                 const float* __restrict__ Weg,
                                                 const float* __restrict__ ag,
                                                 float* __restrict__ outg) {
    __shared__ float pb[2 * PB_F];   // [2][H][520]  ([h][k*64+q])
    __shared__ float scr[32 * 256];  // epilogue partial-combine (32 KB)
    __shared__ float wel[32];
    __shared__ float sl[32];  // [k][h]

    const int t = threadIdx.x, lane = t & 63, wv = t >> 6;
    const int nid = (blockIdx.x & 7) * 64 + (blockIdx.x >> 3);  // chunked XCD swizzle
    const int b = nid >> 7;
    const int k0 = (nid & 127) * KT;
    const int hh = lane >> 4, d4 = lane & 15;

    // fused w_e: 32 threads, 64-step dot each
    if (t < 32) {
        const int h = t >> 3, e = t & 7;
        const float* wrow = Weg + (h * ED_ + e) * D_;
        const float* a3 = ag + h * 192 + 128;
        float a = 0.f;
#pragma unroll
        for (int i = 0; i < D_; ++i) a = fmaf(wrow[i], a3[i], a);
        wel[t] = a;
    }

    const int ek = k0 + wv;  // e-phase k-row for this wave
    const v4f wh1r = *(const v4f*)(Wh1g + (size_t)(b * M_ + ek) * H_);
    const v4f* cvrow = (const v4f*)(cvg + (size_t)(b * M_ + ek) * M_ * ED_);
    const int* mrow = mg + (size_t)(b * M_ + ek) * M_;
    // PV: this wave owns q-rows [q0, q0+8) of each chunk; lane covers (hh,d4)
    const int q0 = wv * 8;
    const float* whb = Whg + ((size_t)(b * H_ + hh) * M_) * D_ + d4 * 4;

    v4f acc[KT];
#pragma unroll
    for (int k = 0; k < KT; ++k) acc[k] = (v4f){0.f, 0.f, 0.f, 0.f};
    float sreg[H_] = {0.f, 0.f, 0.f, 0.f};

    // ---- prologue: chunk-0 inputs into regs ----
    v4f cv0 = cvrow[lane * 2], cv1 = cvrow[lane * 2 + 1];
    int mk = mrow[lane];
    v4f wh2v = *(const v4f*)(Wh2g + (size_t)(b * M_ + lane) * H_);
    __syncthreads();  // wel visible

    for (int c = 0; c < NCH; ++c) {
        float* pbw = pb + (c & 1) * PB_F;
        // ---- e-phase: p = exp(leaky(Wh1 + Wh2 + cv.w_e)) masked ----
#pragma unroll
        for (int h = 0; h < H_; ++h) {
            v4f wa = *(const v4f*)(wel + h * 8);
            v4f wb = *(const v4f*)(wel + h * 8 + 4);
            v4f tt = cv0 * wa + cv1 * wb;
            float ef = (tt.x + tt.y) + (tt.z + tt.w);
            float e = wh1r[h] + wh2v[h] + ef;
            e = fmaxf(e, ALPHA * e);
            float p = (mk > 0) ? __expf(e) : 0.0f;
            pbw[h * PB_H + wv * QC + lane] = p;
            sreg[h] += p;
        }
        __syncthreads();  // pb[c&1] visible (the ONLY barrier per chunk)

        // ---- prefetch chunk c+1 inputs (land during PV) ----
        if (c + 1 < NCH) {
            const int qn = (c + 1) * QC + lane;
            cv0 = cvrow[qn * 2];
            cv1 = cvrow[qn * 2 + 1];
            mk = mrow[qn];
            wh2v = *(const v4f*)(Wh2g + (size_t)(b * M_ + qn) * H_);
        }

        // ---- PV: acc[k] += p[hh][k][q] * Wh[q][hh][d], Wh direct from L2 ----
        {
            const float* whc = whb + (size_t)(c * QC + q0) * D_;
            v4f w[8];
#pragma unroll
            for (int j = 0; j < 8; ++j) w[j] = *(const v4f*)(whc + (size_t)j * D_);
            const float* pbr = pbw + hh * PB_H + q0;
#pragma unroll
            for (int qq = 0; qq < 2; ++qq) {
#pragma unroll
                for (int k = 0; k < KT; ++k) {
                    const v4f pq = *(const v4f*)(pbr + k * QC + qq * 4);  // broadcast
                    v4f a = acc[k];
                    a = f4fma(splat(pq.x), w[qq * 4 + 0], a);
                    a = f4fma(splat(pq.y), w[qq * 4 + 1], a);
                    a = f4fma(splat(pq.z), w[qq * 4 + 2], a);
                    a = f4fma(splat(pq.w), w[qq * 4 + 3], a);
                    acc[k] = a;
                }
            }
        }
        // no second barrier: next e writes the other pb buffer
    }

    // ---- epilogue ----
    // softmax denominators (once)
#pragma unroll
    for (int h = 0; h < H_; ++h) {
        float r = sreg[h];
#pragma unroll
        for (int off = 32; off >= 1; off >>= 1) r += __shfl_xor(r, off);
        if (lane == 0) sl[wv * H_ + h] = r;
    }
    // half-pass A: k-rows 0..3
#pragma unroll
    for (int k = 0; k < 4; ++k) *(v4f*)(scr + (wv * 4 + k) * 256 + lane * 4) = acc[k];
    __syncthreads();
    if (wv < 4) {
        v4f r = (v4f){0.f, 0.f, 0.f, 0.f};
#pragma unroll
        for (int p = 0; p < 8; ++p)
            r += *(const v4f*)(scr + (p * 4 + wv) * 256 + lane * 4);
        r *= splat(1.0f / sl[wv * H_ + hh]);
        *(v4f*)(outg + (size_t)(b * M_ + k0 + wv) * (H_ * D_) + lane * 4) = r;
    }
    __syncthreads();
    // half-pass B: k-rows 4..7
#pragma unroll
    for (int k = 0; k < 4; ++k) *(v4f*)(scr + (wv * 4 + k) * 256 + lane * 4) = acc[4 + k];
    __syncthreads();
    if (wv >= 4) {
        v4f r = (v4f){0.f, 0.f, 0.f, 0.f};
#pragma unroll
        for (int p = 0; p < 8; ++p)
            r += *(const v4f*)(scr + (p * 4 + (wv - 4)) * 256 + lane * 4);
        r *= splat(1.0f / sl[wv * H_ + hh]);
        *(v4f*)(outg + (size_t)(b * M_ + k0 + wv) * (H_ * D_) + lane * 4) = r;
    }
}

extern "C" void kernel_launch(void* const* d_in, const int* in_sizes, int n_in,
                              void* d_out, int out_size, void* d_ws, size_t ws_size,
                              hipStream_t stream) {
    const float* hg = (const float*)d_in[0];
    const int* mg = (const int*)d_in[1];
    const float* cvg = (const float*)d_in[2];
    const float* Wg = (const float*)d_in[3];
    const float* Weg = (const float*)d_in[4];
    const float* ag = (const float*)d_in[5];
    float* outg = (float*)d_out;
    float* ws = (float*)d_ws;
    float* Whg = ws;
    float* Wh1g = ws + WS_WH1;
    float* Wh2g = ws + WS_WH2;

    k_pre<<<1024, 256, 0, stream>>>(hg, Wg, ag, Whg, Wh1g, Wh2g);
    k_main<<<512, 512, 0, stream>>>(cvg, mg, Whg, Wh1g, Wh2g, Weg, ag, outg);
}

// Round 12
// 246.163 us; speedup vs baseline: 1.4749x; 1.0054x over previous
//
#include <hip/hip_runtime.h>
#include <hip/hip_bf16.h>

typedef float v4f __attribute__((ext_vector_type(4)));

#define B_ 4
#define M_ 1024
#define ND_ 64
#define ED_ 8
#define D_ 64
#define H_ 4
#define KT 8           // k-rows per block
#define QC 64          // q-chunk
#define NCH (M_ / QC)  // 16 chunks
#define ALPHA 0.2f

// ws layout (floats): Wh [B][H][M][D], Wh1p [B][M][H], Wh2p [B][M][H]
#define WS_WH1 1048576
#define WS_WH2 1064960

#define PB_H 520          // KT*QC + 8 pad (8-bank shift between h-planes)
#define PB_F (H_ * PB_H)  // 2080

__device__ __forceinline__ v4f splat(float s) { return (v4f){s, s, s, s}; }

__device__ __forceinline__ v4f f4fma(v4f a, v4f b, v4f c) {
#if __has_builtin(__builtin_elementwise_fma)
    return __builtin_elementwise_fma(a, b, c);
#else
    v4f r;
    r.x = fmaf(a.x, b.x, c.x);
    r.y = fmaf(a.y, b.y, c.y);
    r.z = fmaf(a.z, b.z, c.z);
    r.w = fmaf(a.w, b.w, c.w);
    return r;
#endif
}

// ---------------- kernel 1: Wh, Wh1p, Wh2p ----------------
// grid B*H*(M/16) = 1024 blocks x 256. thread = (m:16, d4:16) for one (b,h).
__global__ __launch_bounds__(256) void k_pre(const float* __restrict__ hg,
                                             const float* __restrict__ Wg,
                                             const float* __restrict__ ag,
                                             float* __restrict__ Whg,
                                             float* __restrict__ Wh1g,
                                             float* __restrict__ Wh2g) {
    __shared__ float wl[ND_ * D_];  // 16 KB, linear [i][d]
    __shared__ float hl[16 * 68];   // padded rows (stride 68)
    const int t = threadIdx.x, lane = t & 63, wv = t >> 6;
    const int bid = blockIdx.x;
    const int b = bid >> 8, h = (bid >> 6) & (H_ - 1), mb = bid & 63;
    const int m0 = mb * 16;

    // stage W[h] (16 KB) via async global->LDS, 4 KB per wave
    {
        const float* wsrc = Wg + h * ND_ * D_;
#pragma unroll
        for (int i = 0; i < 4; ++i) {
            const float* s = wsrc + (wv * 4 + i) * 256 + lane * 4;
            __builtin_amdgcn_global_load_lds(
                (const __attribute__((address_space(1))) void*)s,
                (__attribute__((address_space(3))) void*)(wl + (wv * 4 + i) * 256), 16, 0, 0);
        }
    }
    // stage h tile (reg -> padded LDS)
    {
        const int mh = t >> 4, u = t & 15;
        v4f hv = *(const v4f*)(hg + ((size_t)(b * M_) + m0 + mh) * ND_ + u * 4);
        *(v4f*)(hl + mh * 68 + u * 4) = hv;
    }
    __syncthreads();

    const int m = t >> 4, d4 = t & 15;
    v4f acc = {0.f, 0.f, 0.f, 0.f};
#pragma unroll
    for (int i = 0; i < ND_; ++i) {
        v4f w4 = *(const v4f*)(wl + i * 64 + d4 * 4);
        float hs = hl[m * 68 + i];
        acc = f4fma(splat(hs), w4, acc);
    }
    *(v4f*)(Whg + (((size_t)(b * H_ + h)) * M_ + m0 + m) * D_ + d4 * 4) = acc;

    // fused a1/a2 projections (reduce across the 16 d4 lanes of each m)
    v4f a1 = *(const v4f*)(ag + h * 192 + d4 * 4);
    v4f a2 = *(const v4f*)(ag + h * 192 + 64 + d4 * 4);
    v4f p1 = acc * a1, p2 = acc * a2;
    float r1 = (p1.x + p1.y) + (p1.z + p1.w);
    float r2 = (p2.x + p2.y) + (p2.z + p2.w);
#pragma unroll
    for (int off = 8; off >= 1; off >>= 1) {
        r1 += __shfl_xor(r1, off);
        r2 += __shfl_xor(r2, off);
    }
    // packed layout [b][m][h] -> k_main prefetches one coalesced v4f per lane
    if (d4 == 0) {
        Wh1g[((size_t)(b * M_) + m0 + m) * H_ + h] = r1;
        Wh2g[((size_t)(b * M_) + m0 + m) * H_ + h] = r2;
    }
}

// ---------------- kernel 2: fused e -> softmax -> PV ----------------
// Identical structure to round 8. ONE change: amdgpu_waves_per_eu(4,4) pins
// occupancy at 4 waves/SIMD (2 blocks/CU), giving the allocator the full 128
// VGPRs. Rounds 1/2/6/8 all reported VGPR_Count=64 with a >=95-reg live set
// (acc[8]+w[8]+cv prefetch+...) -> the 8-waves/SIMD default heuristic forced
// scratch spills (WRITE_SIZE 29.7 MB vs 4 MB output) and sank the prefetches,
// which is why three different schedules all stalled at ~27% VALUBusy.
__global__ __launch_bounds__(512)
__attribute__((amdgpu_waves_per_eu(4, 4))) void k_main(const float* __restrict__ cvg,
                                                 const int* __restrict__ mg,
                                                 const float* __restrict__ Whg,
                                                 const float* __restrict__ Wh1g,
                                                 const float* __restrict__ Wh2g,
                                                 const float* __restrict__ Weg,
                                                 const float* __restrict__ ag,
                                                 float* __restrict__ outg) {
    __shared__ float pb[2 * PB_F];   // [2][H][520]  ([h][k*64+q])
    __shared__ float scr[32 * 256];  // epilogue partial-combine (32 KB)
    __shared__ float wel[32];
    __shared__ float sl[32];  // [k][h]

    const int t = threadIdx.x, lane = t & 63, wv = t >> 6;
    const int nid = (blockIdx.x & 7) * 64 + (blockIdx.x >> 3);  // chunked XCD swizzle
    const int b = nid >> 7;
    const int k0 = (nid & 127) * KT;
    const int hh = lane >> 4, d4 = lane & 15;

    // fused w_e: 32 threads, 64-step dot each
    if (t < 32) {
        const int h = t >> 3, e = t & 7;
        const float* wrow = Weg + (h * ED_ + e) * D_;
        const float* a3 = ag + h * 192 + 128;
        float a = 0.f;
#pragma unroll
        for (int i = 0; i < D_; ++i) a = fmaf(wrow[i], a3[i], a);
        wel[t] = a;
    }

    const int ek = k0 + wv;  // e-phase k-row for this wave
    const v4f wh1r = *(const v4f*)(Wh1g + (size_t)(b * M_ + ek) * H_);
    const v4f* cvrow = (const v4f*)(cvg + (size_t)(b * M_ + ek) * M_ * ED_);
    const int* mrow = mg + (size_t)(b * M_ + ek) * M_;
    // PV: this wave owns q-rows [q0, q0+8) of each chunk; lane covers (hh,d4)
    const int q0 = wv * 8;
    const float* whb = Whg + ((size_t)(b * H_ + hh) * M_) * D_ + d4 * 4;

    v4f acc[KT];
#pragma unroll
    for (int k = 0; k < KT; ++k) acc[k] = (v4f){0.f, 0.f, 0.f, 0.f};
    float sreg[H_] = {0.f, 0.f, 0.f, 0.f};

    // ---- prologue: chunk-0 inputs into regs ----
    v4f cv0 = cvrow[lane * 2], cv1 = cvrow[lane * 2 + 1];
    int mk = mrow[lane];
    v4f wh2v = *(const v4f*)(Wh2g + (size_t)(b * M_ + lane) * H_);
    __syncthreads();  // wel visible

    for (int c = 0; c < NCH; ++c) {
        float* pbw = pb + (c & 1) * PB_F;
        // ---- e-phase: p = exp(leaky(Wh1 + Wh2 + cv.w_e)) masked ----
#pragma unroll
        for (int h = 0; h < H_; ++h) {
            v4f wa = *(const v4f*)(wel + h * 8);
            v4f wb = *(const v4f*)(wel + h * 8 + 4);
            v4f tt = cv0 * wa + cv1 * wb;
            float ef = (tt.x + tt.y) + (tt.z + tt.w);
            float e = wh1r[h] + wh2v[h] + ef;
            e = fmaxf(e, ALPHA * e);
            float p = (mk > 0) ? __expf(e) : 0.0f;
            pbw[h * PB_H + wv * QC + lane] = p;
            sreg[h] += p;
        }
        __syncthreads();  // pb[c&1] visible (the ONLY barrier per chunk)

        // ---- prefetch chunk c+1 inputs (land during PV) ----
        if (c + 1 < NCH) {
            const int qn = (c + 1) * QC + lane;
            cv0 = cvrow[qn * 2];
            cv1 = cvrow[qn * 2 + 1];
            mk = mrow[qn];
            wh2v = *(const v4f*)(Wh2g + (size_t)(b * M_ + qn) * H_);
        }

        // ---- PV: acc[k] += p[hh][k][q] * Wh[q][hh][d], Wh direct from L2 ----
        {
            const float* whc = whb + (size_t)(c * QC + q0) * D_;
            v4f w[8];
#pragma unroll
            for (int j = 0; j < 8; ++j) w[j] = *(const v4f*)(whc + (size_t)j * D_);
            const float* pbr = pbw + hh * PB_H + q0;
#pragma unroll
            for (int qq = 0; qq < 2; ++qq) {
#pragma unroll
                for (int k = 0; k < KT; ++k) {
                    const v4f pq = *(const v4f*)(pbr + k * QC + qq * 4);  // broadcast
                    v4f a = acc[k];
                    a = f4fma(splat(pq.x), w[qq * 4 + 0], a);
                    a = f4fma(splat(pq.y), w[qq * 4 + 1], a);
                    a = f4fma(splat(pq.z), w[qq * 4 + 2], a);
                    a = f4fma(splat(pq.w), w[qq * 4 + 3], a);
                    acc[k] = a;
                }
            }
        }
        // no second barrier: next e writes the other pb buffer
    }

    // ---- epilogue ----
    // softmax denominators (once)
#pragma unroll
    for (int h = 0; h < H_; ++h) {
        float r = sreg[h];
#pragma unroll
        for (int off = 32; off >= 1; off >>= 1) r += __shfl_xor(r, off);
        if (lane == 0) sl[wv * H_ + h] = r;
    }
    // half-pass A: k-rows 0..3
#pragma unroll
    for (int k = 0; k < 4; ++k) *(v4f*)(scr + (wv * 4 + k) * 256 + lane * 4) = acc[k];
    __syncthreads();
    if (wv < 4) {
        v4f r = (v4f){0.f, 0.f, 0.f, 0.f};
#pragma unroll
        for (int p = 0; p < 8; ++p)
            r += *(const v4f*)(scr + (p * 4 + wv) * 256 + lane * 4);
        r *= splat(1.0f / sl[wv * H_ + hh]);
        *(v4f*)(outg + (size_t)(b * M_ + k0 + wv) * (H_ * D_) + lane * 4) = r;
    }
    __syncthreads();
    // half-pass B: k-rows 4..7
#pragma unroll
    for (int k = 0; k < 4; ++k) *(v4f*)(scr + (wv * 4 + k) * 256 + lane * 4) = acc[4 + k];
    __syncthreads();
    if (wv >= 4) {
        v4f r = (v4f){0.f, 0.f, 0.f, 0.f};
#pragma unroll
        for (int p = 0; p < 8; ++p)
            r += *(const v4f*)(scr + (p * 4 + (wv - 4)) * 256 + lane * 4);
        r *= splat(1.0f / sl[wv * H_ + hh]);
        *(v4f*)(outg + (size_t)(b * M_ + k0 + wv) * (H_ * D_) + lane * 4) = r;
    }
}

extern "C" void kernel_launch(void* const* d_in, const int* in_sizes, int n_in,
                              void* d_out, int out_size, void* d_ws, size_t ws_size,
                              hipStream_t stream) {
    const float* hg = (const float*)d_in[0];
    const int* mg = (const int*)d_in[1];
    const float* cvg = (const float*)d_in[2];
    const float* Wg = (const float*)d_in[3];
    const float* Weg = (const float*)d_in[4];
    const float* ag = (const float*)d_in[5];
    float* outg = (float*)d_out;
    float* ws = (float*)d_ws;
    float* Whg = ws;
    float* Wh1g = ws + WS_WH1;
    float* Wh2g = ws + WS_WH2;

    k_pre<<<1024, 256, 0, stream>>>(hg, Wg, ag, Whg, Wh1g, Wh2g);
    k_main<<<512, 512, 0, stream>>>(cvg, mg, Whg, Wh1g, Wh2g, Weg, ag, outg);
}